// Round 9
// baseline (1854.029 us; speedup 1.0000x reference)
//
#include <hip/hip_runtime.h>
#include <hip/hip_bf16.h>

#define NPG 26
#define EPG 52
#define HDIM 128
#define NC 7
#define NFEAT 9
#define NVOC 119

// ws layout (bytes)
#define ACC_OFF   0      // 2 x f32 accumulators
#define FLAG_OFF  8      // int dtype flag
#define BNSC_OFF  64     // f32[512]
#define BNSHB_OFF 2112   // f32[512]
#define ABL_OFF   4160   // f32[16]
#define LINW_OFF  4224   // f32[128]
#define LINB_OFF  4736   // f32[1]
#define AWT_OFF   4800   // u16[16*256]  (8 KB)
#define WT_OFF    13056  // u16[4*128*256] (256 KB)

typedef unsigned int u32;
typedef unsigned short u16;
typedef float f32x4 __attribute__((ext_vector_type(4)));
typedef short short8 __attribute__((ext_vector_type(8)));

__device__ inline float b2f(u16 u){ union{u32 x; float f;} c; c.x = ((u32)u)<<16; return c.f; }
__device__ inline u16 f2b(float v){ union{ __hip_bfloat16 h; u16 u;} c; c.h = __float2bfloat16(v); return c.u; }
__device__ inline float ldp(const void* p, long long i, int bf){
  return bf ? b2f(((const u16*)p)[i]) : ((const float*)p)[i];
}
__device__ inline f32x4 mfma16(short8 a, short8 b, f32x4 c){
  return __builtin_amdgcn_mfma_f32_16x16x32_bf16(a, b, c, 0, 0, 0);
}
__device__ inline short8 u4s8(uint4 v){ union{uint4 u; short8 s;} c; c.u = v; return c.s; }
__device__ inline u32 pk2(float a, float b){ return (u32)f2b(a) | ((u32)f2b(b) << 16); }

// dtype probe: low 16 bits of packed bf16 pairs are plausible small bf16 values.
__global__ void probe_dtype(const void* w, int* flag) {
  if (threadIdx.x == 0 && blockIdx.x == 0) {
    const u32* p = (const u32*)w;
    int big = 0;
    for (int i = 0; i < 256; ++i) {
      union { u32 x; float f; } c; c.x = (p[i] & 0xffffu) << 16;
      float v = fabsf(c.f);
      if (!(v < 1.0f)) big++;
    }
    *flag = (big < 16) ? 1 : 0;
  }
}

// Repack weights into MFMA-B-fragment-friendly layouts (bf16), fuse BN params.
__global__ __launch_bounds__(256) void diffpool_prep(
    const void* convWl, const void* convbl, const void* convWr,
    const void* bng, const void* bnb, const void* bnrm, const void* bnrv,
    const void* aWl, const void* abl, const void* aWr,
    const void* linW, const void* linb, char* ws)
{
  const int bf = *(const int*)(ws + FLAG_OFF);
  u16* wt    = (u16*)(ws + WT_OFF);
  u16* awt   = (u16*)(ws + AWT_OFF);
  float* bnsc  = (float*)(ws + BNSC_OFF);
  float* bnshb = (float*)(ws + BNSHB_OFF);
  float* ablf  = (float*)(ws + ABL_OFF);
  float* linWf = (float*)(ws + LINW_OFF);
  float* linbf = (float*)(ws + LINB_OFF);
  const int t = blockIdx.x * 256 + threadIdx.x;
  const long long NT = (long long)gridDim.x * 256;
  // Wt[(li*128 + j)*256 + k] = k<128 ? Wl[li][k][j] : Wr[li][k-128][j]
  for (long long o = t; o < 4LL*128*256; o += NT) {
    int li = (int)(o >> 15); int r = (int)(o & 32767); int jj = r >> 8; int k = r & 255;
    float v = (k < 128) ? ldp(convWl, (long long)li*16384 + (long long)k*128 + jj, bf)
                        : ldp(convWr, (long long)li*16384 + (long long)(k-128)*128 + jj, bf);
    wt[o] = f2b(v);
  }
  if (t < 4096) {
    int c = t >> 8, k = t & 255;
    float v = 0.f;
    if (c < NC) v = (k < 128) ? ldp(aWl, (long long)k*NC + c, bf)
                              : ldp(aWr, (long long)(k-128)*NC + c, bf);
    awt[t] = f2b(v);
  }
  if (t < 512) {
    float g  = ldp(bng, t, bf), b = ldp(bnb, t, bf);
    float rm = ldp(bnrm, t, bf), rv = ldp(bnrv, t, bf);
    float bl = ldp(convbl, t, bf);
    float sc = g * rsqrtf(rv + 1e-5f);
    bnsc[t] = sc; bnshb[t] = b - rm*sc + bl*sc;
  }
  if (t < 128) linWf[t] = ldp(linW, t, bf);
  if (t < 16)  ablf[t] = (t < NC) ? ldp(abl, t, bf) : 0.f;
  if (t == 0)  linbf[0] = ldp(linb, 0, bf);
}

__global__ __launch_bounds__(256, 8) void diffpool_main(
    const int* __restrict__ xfeat,
    const int* __restrict__ esrc,
    const int* __restrict__ edst,
    const void* __restrict__ emb,
    void* __restrict__ out,
    char* __restrict__ ws)
{
  const int bfflag = *(const int*)(ws + FLAG_OFF);
  const u16* wt    = (const u16*)(ws + WT_OFF);
  const u16* awt   = (const u16*)(ws + AWT_OFF);
  const float* bnsc  = (const float*)(ws + BNSC_OFF);
  const float* bnshb = (const float*)(ws + BNSHB_OFF);
  const float* ablf  = (const float*)(ws + ABL_OFF);
  const float* linWf = (const float*)(ws + LINW_OFF);
  const float* linbf = (const float*)(ws + LINB_OFF);
  float* accum = (float*)(ws + ACC_OFF);

  // ~19.7 KB LDS -> 8 blocks/CU
  __shared__ alignas(16) u16 ab[32][264];    // [mean | h] per node (reused for pooled [m | x2])
  __shared__ alignas(16) u16 sdT[16][32];    // S^T bf16, zero-padded
  __shared__ float sd_s[NPG][8];             // logits then probs
  __shared__ float red4[4];
  __shared__ int lsrc[EPG], ldst[EPG], celist[EPG];
  __shared__ int cstart[NPG + 1], ccnt[NPG];
  __shared__ float rdeg[NPG];

  const int tid  = threadIdx.x;
  const int g    = blockIdx.x;
  const int w    = tid >> 6;
  const int lane = tid & 63;
  const int l4   = lane >> 4;
  const int lm   = lane & 15;
  const int jc0  = w*32 + lm, jc1 = jc0 + 16;

  // ---------- init ----------
  if (tid < EPG) {
    lsrc[tid] = esrc[(long long)g*EPG + tid] - g*NPG;
    ldst[tid] = edst[(long long)g*EPG + tid] - g*NPG;
  }
  if (tid < NPG) ccnt[tid] = 0;
  ((u32*)sdT)[tid] = 0;                                   // 256 words = whole sdT
  { u32* abz = (u32*)&ab[26][0];                          // zero pad rows 26..31
    for (int i = tid; i < 6*132; i += 256) abz[i] = 0; }
  __syncthreads();
  if (tid < EPG) atomicAdd(&ccnt[ldst[tid]], 1);
  __syncthreads();
  if (tid < 64) {                 // wave-0 prefix scan over 26 counts
    int c = (tid < NPG) ? ccnt[tid] : 0;
    int sc = c;
    #pragma unroll
    for (int off = 1; off < 32; off <<= 1) {
      int o = __shfl_up(sc, off);
      if (tid >= off) sc += o;
    }
    if (tid < NPG) { cstart[tid + 1] = sc; rdeg[tid] = 1.f / fmaxf((float)c, 1.f); }
    if (tid == 0) cstart[0] = 0;
  }
  __syncthreads();
  if (tid < NPG) ccnt[tid] = 0;
  __syncthreads();
  if (tid < EPG) { int d = ldst[tid]; int pos = cstart[d] + atomicAdd(&ccnt[d], 1); celist[pos] = lsrc[tid]; }

  // ---------- atom encoder (2 channels/thread, no LDS feature staging) ----------
  for (int it = tid; it < NPG*64; it += 256) {
    int n = it >> 6, jp = it & 63;
    const int* xfp = xfeat + (long long)g*NPG*NFEAT + n*NFEAT;
    float a0 = 0.f, a1 = 0.f;
    if (bfflag) {
      #pragma unroll
      for (int f = 0; f < NFEAT; ++f) {
        u32 ev = *(const u32*)((const u16*)emb + ((long long)(f*NVOC + xfp[f])*HDIM + 2*jp));
        a0 += b2f((u16)ev); a1 += b2f((u16)(ev >> 16));
      }
    } else {
      #pragma unroll
      for (int f = 0; f < NFEAT; ++f) {
        float2 ev = ((const float2*)emb)[(long long)(f*NVOC + xfp[f])*64 + jp];
        a0 += ev.x; a1 += ev.y;
      }
    }
    *(u32*)&ab[n][128 + 2*jp] = pk2(a0, a1);
  }
  __syncthreads();

  // ---------- 2 SAGE layers ----------
  for (int li = 0; li < 2; ++li) {
    for (int it = tid; it < NPG*64; it += 256) {   // neighbor mean
      int n = it >> 6, jp = it & 63;
      float a0 = 0.f, a1 = 0.f;
      int st = cstart[n], en = cstart[n+1];
      for (int e = st; e < en; ++e) {
        u32 hv = *(const u32*)&ab[celist[e]][128 + 2*jp];
        a0 += b2f((u16)hv); a1 += b2f((u16)(hv >> 16));
      }
      float rd = rdeg[n];
      *(u32*)&ab[n][2*jp] = pk2(a0*rd, a1*rd);
    }
    __syncthreads();

    const u16* wtc0 = wt + (((size_t)li*128 + jc0) << 8) + 8*l4;
    const u16* wtc1 = wt + (((size_t)li*128 + jc1) << 8) + 8*l4;
    f32x4 a00 = {0,0,0,0}, a01 = {0,0,0,0}, a10 = {0,0,0,0}, a11 = {0,0,0,0};
    uint4 bA = *(const uint4*)(wtc0);
    uint4 bB = *(const uint4*)(wtc1);
    #pragma unroll
    for (int c = 0; c < 8; ++c) {
      short8 b0 = u4s8(bA), b1 = u4s8(bB);
      if (c < 7) {
        bA = *(const uint4*)(wtc0 + (c+1)*32);
        bB = *(const uint4*)(wtc1 + (c+1)*32);
      }
      short8 af0 = *(const short8*)&ab[lm][c*32 + 8*l4];
      short8 af1 = *(const short8*)&ab[16 + lm][c*32 + 8*l4];
      a00 = mfma16(af0, b0, a00); a01 = mfma16(af0, b1, a01);
      a10 = mfma16(af1, b0, a10); a11 = mfma16(af1, b1, a11);
    }
    __syncthreads();   // A reads done before h writes

    float sc0 = bnsc[li*128 + jc0], sb0 = bnshb[li*128 + jc0];
    float sc1 = bnsc[li*128 + jc1], sb1 = bnshb[li*128 + jc1];
    #pragma unroll
    for (int rr = 0; rr < 4; ++rr) {
      int n = 4*l4 + rr;
      float v0 = fmaxf(fmaf(a00[rr], sc0, sb0), 0.f);
      float v1 = fmaxf(fmaf(a01[rr], sc1, sb1), 0.f);
      ab[n][128+jc0] = f2b(v0 + b2f(ab[n][128+jc0]));
      ab[n][128+jc1] = f2b(v1 + b2f(ab[n][128+jc1]));
      int n1 = 16 + 4*l4 + rr;
      if (n1 < NPG) {
        float u0 = fmaxf(fmaf(a10[rr], sc0, sb0), 0.f);
        float u1 = fmaxf(fmaf(a11[rr], sc1, sb1), 0.f);
        ab[n1][128+jc0] = f2b(u0 + b2f(ab[n1][128+jc0]));
        ab[n1][128+jc1] = f2b(u1 + b2f(ab[n1][128+jc1]));
      }
    }
    __syncthreads();
  }

  // ---------- assignment conv ----------
  for (int it = tid; it < NPG*64; it += 256) {
    int n = it >> 6, jp = it & 63;
    float a0 = 0.f, a1 = 0.f;
    int st = cstart[n], en = cstart[n+1];
    for (int e = st; e < en; ++e) {
      u32 hv = *(const u32*)&ab[celist[e]][128 + 2*jp];
      a0 += b2f((u16)hv); a1 += b2f((u16)(hv >> 16));
    }
    float rd = rdeg[n];
    *(u32*)&ab[n][2*jp] = pk2(a0*rd, a1*rd);
  }
  __syncthreads();
  if (w < 2) {
    const u16* ar = awt + ((size_t)lm << 8) + 8*l4;
    f32x4 acc = {0,0,0,0};
    uint4 bv4 = *(const uint4*)(ar);
    #pragma unroll
    for (int c = 0; c < 8; ++c) {
      short8 bv = u4s8(bv4);
      if (c < 7) bv4 = *(const uint4*)(ar + (c+1)*32);
      short8 af = *(const short8*)&ab[w*16 + lm][c*32 + 8*l4];
      acc = mfma16(af, bv, acc);
    }
    float bl = ablf[lm];
    #pragma unroll
    for (int rr = 0; rr < 4; ++rr) {
      int n = w*16 + 4*l4 + rr;
      if (n < NPG && lm < NC) sd_s[n][lm] = acc[rr] + bl;
    }
  }
  __syncthreads();

  // ---------- softmax + entropy ----------
  {
    float ent = 0.f;
    if (tid < NPG) {
      float mx = sd_s[tid][0];
      #pragma unroll
      for (int c = 1; c < NC; ++c) mx = fmaxf(mx, sd_s[tid][c]);
      float ex[NC], se = 0.f, dot = 0.f;
      #pragma unroll
      for (int c = 0; c < NC; ++c) {
        float d = sd_s[tid][c] - mx;
        ex[c] = expf(d); se += ex[c]; dot = fmaf(ex[c], d, dot);
      }
      float inv = 1.f / se;
      #pragma unroll
      for (int c = 0; c < NC; ++c) sd_s[tid][c] = ex[c]*inv;
      ent = logf(se) - dot*inv;
    }
    if (w == 0) {                       // wave-0 reduce of entropy
      float v = ent;
      #pragma unroll
      for (int off = 32; off >= 1; off >>= 1) v += __shfl_down(v, off);
      if (lane == 0) atomicAdd(&accum[1], v);
    }
  }
  __syncthreads();                      // probs final
  if (tid < NPG*NC) { int n = tid/7, c = tid%7; sdT[c][n] = f2b(sd_s[n][c]); }

  // ---------- link loss: sum_e mult(e) - 2*sum_e ss_e + ||S^T S||_F^2 ----------
  {
    float lv = 0.f;
    if (tid < EPG) {
      int key = lsrc[tid]*32 + ldst[tid];
      int cnt = 0;
      for (int e = 0; e < EPG; ++e) cnt += ((lsrc[e]*32 + ldst[e]) == key) ? 1 : 0;
      float ss = 0.f;
      #pragma unroll
      for (int c = 0; c < NC; ++c) ss = fmaf(sd_s[lsrc[tid]][c], sd_s[ldst[tid]][c], ss);
      lv = (float)cnt - 2.f*ss;
    } else if (tid >= 64 && tid < 64 + NC*NC) {
      int idx = tid - 64, c1 = idx/7, c2 = idx%7;
      float m = 0.f;
      for (int n = 0; n < NPG; ++n) m = fmaf(sd_s[n][c1], sd_s[n][c2], m);
      lv = m*m;
    }
    #pragma unroll
    for (int off = 32; off >= 1; off >>= 1) lv += __shfl_down(lv, off);
    if (lane == 0) red4[w] = lv;
  }
  __syncthreads();                      // red4 ready; sdT ready
  if (tid == 0) atomicAdd(&accum[0], red4[0] + red4[1] + red4[2] + red4[3]);

  // ---------- x2 = S^T h (MFMA, results held in regs) ----------
  f32x4 e0 = {0,0,0,0}, e1 = {0,0,0,0};
  {
    short8 af = *(const short8*)&sdT[lm][8*l4];
    short8 b0, b1;
    #pragma unroll
    for (int i = 0; i < 8; ++i) {
      int n = 8*l4 + i;
      b0[i] = (short)ab[n][128+jc0]; b1[i] = (short)ab[n][128+jc1];
    }
    e0 = mfma16(af, b0, e0); e1 = mfma16(af, b1, e1);
  }
  __syncthreads();                      // all h reads done
  #pragma unroll
  for (int rr = 0; rr < 4; ++rr) {      // overwrite ab rows 0..6 with x2
    int cc = 4*l4 + rr;
    if (cc < NC) { ab[cc][128+jc0] = f2b(e0[rr]); ab[cc][128+jc1] = f2b(e1[rr]); }
  }
  __syncthreads();

  // ---------- pooled dense layers (A rows 0..6 valid; 7..15 garbage, discarded) ----------
  for (int li = 2; li < 4; ++li) {
    if (tid < 64) {
      int jp = tid; float s0 = 0.f, s1 = 0.f;
      #pragma unroll
      for (int c = 0; c < NC; ++c) {
        u32 v = *(const u32*)&ab[c][128 + 2*jp];
        s0 += b2f((u16)v); s1 += b2f((u16)(v >> 16));
      }
      u32 pkv = pk2(s0*(1.f/7.f), s1*(1.f/7.f));
      #pragma unroll
      for (int c = 0; c < NC; ++c) *(u32*)&ab[c][2*jp] = pkv;
    }
    __syncthreads();
    const u16* wtc0 = wt + (((size_t)li*128 + jc0) << 8) + 8*l4;
    const u16* wtc1 = wt + (((size_t)li*128 + jc1) << 8) + 8*l4;
    f32x4 a0 = {0,0,0,0}, a1 = {0,0,0,0};
    uint4 bA = *(const uint4*)(wtc0);
    uint4 bB = *(const uint4*)(wtc1);
    #pragma unroll
    for (int c = 0; c < 8; ++c) {
      short8 b0 = u4s8(bA), b1 = u4s8(bB);
      if (c < 7) {
        bA = *(const uint4*)(wtc0 + (c+1)*32);
        bB = *(const uint4*)(wtc1 + (c+1)*32);
      }
      short8 af = *(const short8*)&ab[lm][c*32 + 8*l4];
      a0 = mfma16(af, b0, a0); a1 = mfma16(af, b1, a1);
    }
    __syncthreads();
    float sc0 = bnsc[li*128 + jc0], sb0 = bnshb[li*128 + jc0];
    float sc1 = bnsc[li*128 + jc1], sb1 = bnshb[li*128 + jc1];
    #pragma unroll
    for (int rr = 0; rr < 4; ++rr) {
      int cc = 4*l4 + rr;
      if (cc < NC) {
        float v0 = fmaf(a0[rr], sc0, sb0) + b2f(ab[cc][128+jc0]);
        float v1 = fmaf(a1[rr], sc1, sb1) + b2f(ab[cc][128+jc1]);
        ab[cc][128+jc0] = f2b(v0);
        ab[cc][128+jc1] = f2b(v1);
      }
    }
    __syncthreads();
  }

  // ---------- readout ----------
  if (tid < 64) {
    int jp = tid; float s0 = 0.f, s1 = 0.f;
    #pragma unroll
    for (int c = 0; c < NC; ++c) {
      u32 v = *(const u32*)&ab[c][128 + 2*jp];
      s0 += b2f((u16)v); s1 += b2f((u16)(v >> 16));
    }
    float v = (s0*(1.f/7.f))*linWf[2*jp] + (s1*(1.f/7.f))*linWf[2*jp+1];
    #pragma unroll
    for (int off = 32; off >= 1; off >>= 1) v += __shfl_down(v, off);
    if (tid == 0) {
      float z = v + linbf[0];
      float o = 1.f / (1.f + expf(-z));
      if (bfflag) ((u16*)out)[g] = f2b(o); else ((float*)out)[g] = o;
    }
  }
}

__global__ void diffpool_finalize(const char* __restrict__ ws, void* __restrict__ out, int nb) {
  if (threadIdx.x == 0 && blockIdx.x == 0) {
    const float* accum = (const float*)(ws + ACC_OFF);
    const int bf = *(const int*)(ws + FLAG_OFF);
    float link = sqrtf(fmaxf(accum[0], 0.f)) / ((float)nb * (float)(NPG*NPG));
    float ent  = accum[1] / ((float)nb * (float)NPG);
    if (bf) { ((u16*)out)[nb] = f2b(link); ((u16*)out)[nb+1] = f2b(ent); }
    else    { ((float*)out)[nb] = link;    ((float*)out)[nb+1] = ent; }
  }
}

extern "C" void kernel_launch(void* const* d_in, const int* in_sizes, int n_in,
                              void* d_out, int out_size, void* d_ws, size_t ws_size,
                              hipStream_t stream) {
  const int* x  = (const int*)d_in[0];
  const int* ei = (const int*)d_in[1];
  const int ntot = in_sizes[0] / NFEAT;
  const int nb   = ntot / NPG;
  const int* esrc = ei;
  const int* edst = ei + (long long)nb * EPG;
  char* ws = (char*)d_ws;
  int* flag = (int*)(ws + FLAG_OFF);

  hipMemsetAsync(ws, 0, 16, stream);
  probe_dtype<<<1, 64, 0, stream>>>(d_in[4], flag);
  diffpool_prep<<<256, 256, 0, stream>>>(
      d_in[4], d_in[5], d_in[6],
      d_in[7], d_in[8], d_in[9], d_in[10],
      d_in[11], d_in[12], d_in[13], d_in[14], d_in[15], ws);
  diffpool_main<<<nb, 256, 0, stream>>>(x, esrc, edst, d_in[3], d_out, ws);
  diffpool_finalize<<<1, 64, 0, stream>>>(ws, d_out, nb);
}

// Round 10
// 994.093 us; speedup vs baseline: 1.8650x; 1.8650x over previous
//
#include <hip/hip_runtime.h>
#include <hip/hip_bf16.h>

#define NPG 26
#define EPG 52
#define HDIM 128
#define NC 7
#define NFEAT 9
#define NVOC 119

// ws layout (bytes)
#define ACC_OFF   0      // 2 x f32 accumulators
#define FLAG_OFF  8      // int dtype flag
#define BNSC_OFF  64     // f32[512]
#define BNSHB_OFF 2112   // f32[512]
#define ABL_OFF   4160   // f32[16]
#define LINW_OFF  4224   // f32[128]
#define LINB_OFF  4736   // f32[1]
#define AWT_OFF   4800   // u16[16*256]  (8 KB)
#define WT_OFF    13056  // u16[4*8*128*32] (256 KB), chunk-major fragment-ready

typedef unsigned int u32;
typedef unsigned short u16;
typedef float f32x4 __attribute__((ext_vector_type(4)));
typedef short short8 __attribute__((ext_vector_type(8)));

__device__ inline float b2f(u16 u){ union{u32 x; float f;} c; c.x = ((u32)u)<<16; return c.f; }
__device__ inline u16 f2b(float v){ union{ __hip_bfloat16 h; u16 u;} c; c.h = __float2bfloat16(v); return c.u; }
__device__ inline float ldp(const void* p, long long i, int bf){
  return bf ? b2f(((const u16*)p)[i]) : ((const float*)p)[i];
}
__device__ inline f32x4 mfma16(short8 a, short8 b, f32x4 c){
  return __builtin_amdgcn_mfma_f32_16x16x32_bf16(a, b, c, 0, 0, 0);
}
__device__ inline short8 u4s8(uint4 v){ union{uint4 u; short8 s;} c; c.u = v; return c.s; }
__device__ inline u32 pk2(float a, float b){ return (u32)f2b(a) | ((u32)f2b(b) << 16); }

__global__ void probe_dtype(const void* w, int* flag) {
  if (threadIdx.x == 0 && blockIdx.x == 0) {
    const u32* p = (const u32*)w;
    int big = 0;
    for (int i = 0; i < 256; ++i) {
      union { u32 x; float f; } c; c.x = (p[i] & 0xffffu) << 16;
      float v = fabsf(c.f);
      if (!(v < 1.0f)) big++;
    }
    *flag = (big < 16) ? 1 : 0;
  }
}

// Repack weights: chunk-major fragment-ready wt[li][c][j][kk] = W(k=c*32+kk -> Wl|Wr)[.][j]
__global__ __launch_bounds__(256) void diffpool_prep(
    const void* convWl, const void* convbl, const void* convWr,
    const void* bng, const void* bnb, const void* bnrm, const void* bnrv,
    const void* aWl, const void* abl, const void* aWr,
    const void* linW, const void* linb, char* ws)
{
  const int bf = *(const int*)(ws + FLAG_OFF);
  u16* wt    = (u16*)(ws + WT_OFF);
  u16* awt   = (u16*)(ws + AWT_OFF);
  float* bnsc  = (float*)(ws + BNSC_OFF);
  float* bnshb = (float*)(ws + BNSHB_OFF);
  float* ablf  = (float*)(ws + ABL_OFF);
  float* linWf = (float*)(ws + LINW_OFF);
  float* linbf = (float*)(ws + LINB_OFF);
  const int t = blockIdx.x * 256 + threadIdx.x;
  const long long NT = (long long)gridDim.x * 256;
  for (long long o = t; o < 4LL*8*128*32; o += NT) {
    int kk = (int)(o & 31); int j = (int)((o >> 5) & 127);
    int c = (int)((o >> 12) & 7); int li = (int)(o >> 15);
    int k = c*32 + kk;
    float v = (k < 128) ? ldp(convWl, (long long)li*16384 + (long long)k*128 + j, bf)
                        : ldp(convWr, (long long)li*16384 + (long long)(k-128)*128 + j, bf);
    wt[o] = f2b(v);
  }
  if (t < 4096) {
    int c = t >> 8, k = t & 255;
    float v = 0.f;
    if (c < NC) v = (k < 128) ? ldp(aWl, (long long)k*NC + c, bf)
                              : ldp(aWr, (long long)(k-128)*NC + c, bf);
    awt[t] = f2b(v);
  }
  if (t < 512) {
    float gg = ldp(bng, t, bf), b = ldp(bnb, t, bf);
    float rm = ldp(bnrm, t, bf), rv = ldp(bnrv, t, bf);
    float bl = ldp(convbl, t, bf);
    float sc = gg * rsqrtf(rv + 1e-5f);
    bnsc[t] = sc; bnshb[t] = b - rm*sc + bl*sc;
  }
  if (t < 128) linWf[t] = ldp(linW, t, bf);
  if (t < 16)  ablf[t] = (t < NC) ? ldp(abl, t, bf) : 0.f;
  if (t == 0)  linbf[0] = ldp(linb, 0, bf);
}

// 512 threads = 2 graphs per block (grp 0/1, 4 waves each), shared weight staging.
__global__ __launch_bounds__(512, 4) void diffpool_main(
    const int* __restrict__ xfeat,
    const int* __restrict__ esrc,
    const int* __restrict__ edst,
    const void* __restrict__ emb,
    void* __restrict__ out,
    char* __restrict__ ws)
{
  const int bfflag = *(const int*)(ws + FLAG_OFF);
  const u16* wt    = (const u16*)(ws + WT_OFF);
  const u16* awt   = (const u16*)(ws + AWT_OFF);
  const float* bnsc  = (const float*)(ws + BNSC_OFF);
  const float* bnshb = (const float*)(ws + BNSHB_OFF);
  const float* ablf  = (const float*)(ws + ABL_OFF);
  const float* linWf = (const float*)(ws + LINW_OFF);
  const float* linbf = (const float*)(ws + LINB_OFF);
  float* accum = (float*)(ws + ACC_OFF);

  __shared__ alignas(16) u16 ab[2][32][264];   // per graph: [mean | h]
  __shared__ alignas(16) u32 wst[128][20];     // staged chunk [j][32k bf16 + pad], 80B rows
  __shared__ alignas(16) u16 sdT[2][16][32];   // S^T per graph
  __shared__ float sd_s[2][NPG][8];
  __shared__ float redg[2][4];
  __shared__ int lsrc[2][EPG], ldst[2][EPG], celist[2][EPG];
  __shared__ int cstart[2][NPG+1], ccnt[2][NPG];
  __shared__ float rdeg[2][NPG];

  const int tid  = threadIdx.x;
  const int grp  = tid >> 8;
  const int gt   = tid & 255;
  const long long g = (long long)blockIdx.x * 2 + grp;
  const int gw   = (tid >> 6) & 3;
  const int lane = tid & 63;
  const int l4   = lane >> 4;
  const int lm   = lane & 15;
  const int jc0  = gw*32 + lm, jc1 = jc0 + 16;

  // ---------- init / CSR ----------
  if (gt < EPG) {
    lsrc[grp][gt] = esrc[g*EPG + gt] - (int)(g*NPG);
    ldst[grp][gt] = edst[g*EPG + gt] - (int)(g*NPG);
  }
  if (gt < NPG) ccnt[grp][gt] = 0;
  ((u32*)sdT)[tid] = 0;                              // 512 u32 = whole sdT
  { u32* abz = (u32*)&ab[grp][26][0];                // zero pad rows 26..31 (mean+h)
    for (int i = gt; i < 6*132; i += 256) abz[i] = 0; }
  __syncthreads();
  if (gt < EPG) atomicAdd(&ccnt[grp][ldst[grp][gt]], 1);
  __syncthreads();
  if (gw == 0) {                                     // per-group wave-0 prefix scan
    int c = (lane < NPG) ? ccnt[grp][lane] : 0;
    int sc = c;
    #pragma unroll
    for (int off = 1; off < 32; off <<= 1) {
      int o = __shfl_up(sc, off);
      if (lane >= off) sc += o;
    }
    if (lane < NPG) { cstart[grp][lane + 1] = sc; rdeg[grp][lane] = 1.f / fmaxf((float)c, 1.f); }
    if (lane == 0) cstart[grp][0] = 0;
  }
  __syncthreads();
  if (gt < NPG) ccnt[grp][gt] = 0;
  __syncthreads();
  if (gt < EPG) {
    int d = ldst[grp][gt];
    int pos = cstart[grp][d] + atomicAdd(&ccnt[grp][d], 1);
    celist[grp][pos] = lsrc[grp][gt];
  }

  // ---------- atom encoder ----------
  for (int it = gt; it < NPG*64; it += 256) {
    int n = it >> 6, jp = it & 63;
    const int* xfp = xfeat + g*NPG*NFEAT + n*NFEAT;
    float a0 = 0.f, a1 = 0.f;
    if (bfflag) {
      #pragma unroll
      for (int f = 0; f < NFEAT; ++f) {
        u32 ev = *(const u32*)((const u16*)emb + ((long long)(f*NVOC + xfp[f])*HDIM + 2*jp));
        a0 += b2f((u16)ev); a1 += b2f((u16)(ev >> 16));
      }
    } else {
      #pragma unroll
      for (int f = 0; f < NFEAT; ++f) {
        float2 ev = ((const float2*)emb)[(long long)(f*NVOC + xfp[f])*64 + jp];
        a0 += ev.x; a1 += ev.y;
      }
    }
    *(u32*)&ab[grp][n][128 + 2*jp] = pk2(a0, a1);
  }
  __syncthreads();

  // ---------- 2 SAGE layers ----------
  for (int li = 0; li < 2; ++li) {
    for (int it = gt; it < NPG*64; it += 256) {      // neighbor mean
      int n = it >> 6, jp = it & 63;
      float a0 = 0.f, a1 = 0.f;
      int st = cstart[grp][n], en = cstart[grp][n+1];
      for (int e = st; e < en; ++e) {
        u32 hv = *(const u32*)&ab[grp][celist[grp][e]][128 + 2*jp];
        a0 += b2f((u16)hv); a1 += b2f((u16)(hv >> 16));
      }
      float rd = rdeg[grp][n];
      *(u32*)&ab[grp][n][2*jp] = pk2(a0*rd, a1*rd);
    }
    __syncthreads();

    // GEMM: 8 chunks, cooperative staging (512 thr x 16B = 8KB chunk), frag-ready reads
    const u16* wsrc = wt + ((size_t)li << 15) + (size_t)tid * 8;
    uint4 pre = *(const uint4*)(wsrc);               // chunk 0
    f32x4 a00 = {0,0,0,0}, a01 = {0,0,0,0}, a10 = {0,0,0,0}, a11 = {0,0,0,0};
    #pragma unroll
    for (int c = 0; c < 8; ++c) {
      if (c) __syncthreads();                        // prev chunk reads done
      *(uint4*)&wst[tid >> 2][(tid & 3) * 4] = pre;
      if (c < 7) pre = *(const uint4*)(wsrc + ((size_t)(c+1) << 12));
      __syncthreads();                               // chunk visible
      short8 b0 = *(const short8*)&wst[jc0][4*l4];
      short8 b1 = *(const short8*)&wst[jc1][4*l4];
      short8 af0 = *(const short8*)&ab[grp][lm][c*32 + 8*l4];
      short8 af1 = *(const short8*)&ab[grp][16 + lm][c*32 + 8*l4];
      a00 = mfma16(af0, b0, a00); a01 = mfma16(af0, b1, a01);
      a10 = mfma16(af1, b0, a10); a11 = mfma16(af1, b1, a11);
    }
    __syncthreads();                                 // A reads done before h writes

    float sc0 = bnsc[li*128 + jc0], sb0 = bnshb[li*128 + jc0];
    float sc1 = bnsc[li*128 + jc1], sb1 = bnshb[li*128 + jc1];
    #pragma unroll
    for (int rr = 0; rr < 4; ++rr) {
      int n = 4*l4 + rr;
      float v0 = fmaxf(fmaf(a00[rr], sc0, sb0), 0.f);
      float v1 = fmaxf(fmaf(a01[rr], sc1, sb1), 0.f);
      ab[grp][n][128+jc0] = f2b(v0 + b2f(ab[grp][n][128+jc0]));
      ab[grp][n][128+jc1] = f2b(v1 + b2f(ab[grp][n][128+jc1]));
      int n1 = 16 + 4*l4 + rr;
      if (n1 < NPG) {
        float u0 = fmaxf(fmaf(a10[rr], sc0, sb0), 0.f);
        float u1 = fmaxf(fmaf(a11[rr], sc1, sb1), 0.f);
        ab[grp][n1][128+jc0] = f2b(u0 + b2f(ab[grp][n1][128+jc0]));
        ab[grp][n1][128+jc1] = f2b(u1 + b2f(ab[grp][n1][128+jc1]));
      }
    }
    __syncthreads();
  }

  // ---------- assignment conv ----------
  for (int it = gt; it < NPG*64; it += 256) {
    int n = it >> 6, jp = it & 63;
    float a0 = 0.f, a1 = 0.f;
    int st = cstart[grp][n], en = cstart[grp][n+1];
    for (int e = st; e < en; ++e) {
      u32 hv = *(const u32*)&ab[grp][celist[grp][e]][128 + 2*jp];
      a0 += b2f((u16)hv); a1 += b2f((u16)(hv >> 16));
    }
    float rd = rdeg[grp][n];
    *(u32*)&ab[grp][n][2*jp] = pk2(a0*rd, a1*rd);
  }
  __syncthreads();
  if (gw < 2) {
    const u16* ar = awt + ((size_t)lm << 8) + 8*l4;
    f32x4 acc = {0,0,0,0};
    uint4 bv4 = *(const uint4*)(ar);
    #pragma unroll
    for (int c = 0; c < 8; ++c) {
      short8 bv = u4s8(bv4);
      if (c < 7) bv4 = *(const uint4*)(ar + (c+1)*32);
      short8 af = *(const short8*)&ab[grp][gw*16 + lm][c*32 + 8*l4];
      acc = mfma16(af, bv, acc);
    }
    float bl = ablf[lm];
    #pragma unroll
    for (int rr = 0; rr < 4; ++rr) {
      int n = gw*16 + 4*l4 + rr;
      if (n < NPG && lm < NC) sd_s[grp][n][lm] = acc[rr] + bl;
    }
  }
  __syncthreads();

  // ---------- softmax + entropy ----------
  {
    float ent = 0.f;
    if (gt < NPG) {
      float mx = sd_s[grp][gt][0];
      #pragma unroll
      for (int c = 1; c < NC; ++c) mx = fmaxf(mx, sd_s[grp][gt][c]);
      float ex[NC], se = 0.f, dot = 0.f;
      #pragma unroll
      for (int c = 0; c < NC; ++c) {
        float d = sd_s[grp][gt][c] - mx;
        ex[c] = expf(d); se += ex[c]; dot = fmaf(ex[c], d, dot);
      }
      float inv = 1.f / se;
      #pragma unroll
      for (int c = 0; c < NC; ++c) sd_s[grp][gt][c] = ex[c]*inv;
      ent = logf(se) - dot*inv;
    }
    if (gw == 0) {
      float v = ent;
      #pragma unroll
      for (int off = 32; off >= 1; off >>= 1) v += __shfl_down(v, off);
      if (lane == 0) atomicAdd(&accum[1], v);
    }
  }
  __syncthreads();
  if (gt < NPG*NC) { int n = gt/7, c = gt%7; sdT[grp][c][n] = f2b(sd_s[grp][n][c]); }

  // ---------- link loss ----------
  {
    float lv = 0.f;
    if (gt < EPG) {
      int key = lsrc[grp][gt]*32 + ldst[grp][gt];
      int cnt = 0;
      for (int e = 0; e < EPG; ++e) cnt += ((lsrc[grp][e]*32 + ldst[grp][e]) == key) ? 1 : 0;
      float ss = 0.f;
      #pragma unroll
      for (int c = 0; c < NC; ++c) ss = fmaf(sd_s[grp][lsrc[grp][gt]][c], sd_s[grp][ldst[grp][gt]][c], ss);
      lv = (float)cnt - 2.f*ss;
    } else if (gt >= 64 && gt < 64 + NC*NC) {
      int idx = gt - 64, c1 = idx/7, c2 = idx%7;
      float m = 0.f;
      for (int n = 0; n < NPG; ++n) m = fmaf(sd_s[grp][n][c1], sd_s[grp][n][c2], m);
      lv = m*m;
    }
    #pragma unroll
    for (int off = 32; off >= 1; off >>= 1) lv += __shfl_down(lv, off);
    if (lane == 0) redg[grp][gw] = lv;
  }
  __syncthreads();
  if (gt == 0) atomicAdd(&accum[0], redg[grp][0] + redg[grp][1] + redg[grp][2] + redg[grp][3]);

  // ---------- x2 = S^T h (regs) ----------
  f32x4 e0 = {0,0,0,0}, e1 = {0,0,0,0};
  {
    short8 af = *(const short8*)&sdT[grp][lm][8*l4];
    short8 b0, b1;
    #pragma unroll
    for (int i = 0; i < 8; ++i) {
      int n = 8*l4 + i;
      b0[i] = (short)ab[grp][n][128+jc0]; b1[i] = (short)ab[grp][n][128+jc1];
    }
    e0 = mfma16(af, b0, e0); e1 = mfma16(af, b1, e1);
  }
  __syncthreads();
  #pragma unroll
  for (int rr = 0; rr < 4; ++rr) {
    int cc = 4*l4 + rr;
    if (cc < NC) { ab[grp][cc][128+jc0] = f2b(e0[rr]); ab[grp][cc][128+jc1] = f2b(e1[rr]); }
  }
  __syncthreads();

  // ---------- pooled dense layers ----------
  for (int li = 2; li < 4; ++li) {
    if (gt < 64) {
      int jp = gt; float s0 = 0.f, s1 = 0.f;
      #pragma unroll
      for (int c = 0; c < NC; ++c) {
        u32 v = *(const u32*)&ab[grp][c][128 + 2*jp];
        s0 += b2f((u16)v); s1 += b2f((u16)(v >> 16));
      }
      u32 pkv = pk2(s0*(1.f/7.f), s1*(1.f/7.f));
      #pragma unroll
      for (int c = 0; c < NC; ++c) *(u32*)&ab[grp][c][2*jp] = pkv;
    }
    __syncthreads();
    const u16* wsrc = wt + ((size_t)li << 15) + (size_t)tid * 8;
    uint4 pre = *(const uint4*)(wsrc);
    f32x4 a0 = {0,0,0,0}, a1 = {0,0,0,0};
    #pragma unroll
    for (int c = 0; c < 8; ++c) {
      if (c) __syncthreads();
      *(uint4*)&wst[tid >> 2][(tid & 3) * 4] = pre;
      if (c < 7) pre = *(const uint4*)(wsrc + ((size_t)(c+1) << 12));
      __syncthreads();
      short8 b0 = *(const short8*)&wst[jc0][4*l4];
      short8 b1 = *(const short8*)&wst[jc1][4*l4];
      short8 af = *(const short8*)&ab[grp][lm][c*32 + 8*l4];
      a0 = mfma16(af, b0, a0); a1 = mfma16(af, b1, a1);
    }
    __syncthreads();
    float sc0 = bnsc[li*128 + jc0], sb0 = bnshb[li*128 + jc0];
    float sc1 = bnsc[li*128 + jc1], sb1 = bnshb[li*128 + jc1];
    #pragma unroll
    for (int rr = 0; rr < 4; ++rr) {
      int cc = 4*l4 + rr;
      if (cc < NC) {
        float v0 = fmaf(a0[rr], sc0, sb0) + b2f(ab[grp][cc][128+jc0]);
        float v1 = fmaf(a1[rr], sc1, sb1) + b2f(ab[grp][cc][128+jc1]);
        ab[grp][cc][128+jc0] = f2b(v0);
        ab[grp][cc][128+jc1] = f2b(v1);
      }
    }
    __syncthreads();
  }

  // ---------- readout ----------
  if (gt < 64) {
    int jp = gt; float s0 = 0.f, s1 = 0.f;
    #pragma unroll
    for (int c = 0; c < NC; ++c) {
      u32 v = *(const u32*)&ab[grp][c][128 + 2*jp];
      s0 += b2f((u16)v); s1 += b2f((u16)(v >> 16));
    }
    float v = (s0*(1.f/7.f))*linWf[2*jp] + (s1*(1.f/7.f))*linWf[2*jp+1];
    #pragma unroll
    for (int off = 32; off >= 1; off >>= 1) v += __shfl_down(v, off);
    if (gt == 0) {
      float z = v + linbf[0];
      float o = 1.f / (1.f + expf(-z));
      if (bfflag) ((u16*)out)[g] = f2b(o); else ((float*)out)[g] = o;
    }
  }
}

__global__ void diffpool_finalize(const char* __restrict__ ws, void* __restrict__ out, int nb) {
  if (threadIdx.x == 0 && blockIdx.x == 0) {
    const float* accum = (const float*)(ws + ACC_OFF);
    const int bf = *(const int*)(ws + FLAG_OFF);
    float link = sqrtf(fmaxf(accum[0], 0.f)) / ((float)nb * (float)(NPG*NPG));
    float ent  = accum[1] / ((float)nb * (float)NPG);
    if (bf) { ((u16*)out)[nb] = f2b(link); ((u16*)out)[nb+1] = f2b(ent); }
    else    { ((float*)out)[nb] = link;    ((float*)out)[nb+1] = ent; }
  }
}

extern "C" void kernel_launch(void* const* d_in, const int* in_sizes, int n_in,
                              void* d_out, int out_size, void* d_ws, size_t ws_size,
                              hipStream_t stream) {
  const int* x  = (const int*)d_in[0];
  const int* ei = (const int*)d_in[1];
  const int ntot = in_sizes[0] / NFEAT;
  const int nb   = ntot / NPG;
  const int* esrc = ei;
  const int* edst = ei + (long long)nb * EPG;
  char* ws = (char*)d_ws;
  int* flag = (int*)(ws + FLAG_OFF);

  hipMemsetAsync(ws, 0, 16, stream);
  probe_dtype<<<1, 64, 0, stream>>>(d_in[4], flag);
  diffpool_prep<<<256, 256, 0, stream>>>(
      d_in[4], d_in[5], d_in[6],
      d_in[7], d_in[8], d_in[9], d_in[10],
      d_in[11], d_in[12], d_in[13], d_in[14], d_in[15], ws);
  diffpool_main<<<nb/2, 512, 0, stream>>>(x, esrc, edst, d_in[3], d_out, ws);
  diffpool_finalize<<<1, 64, 0, stream>>>(ws, d_out, nb);
}